// Round 6
// baseline (9837.011 us; speedup 1.0000x reference)
//
#include <hip/hip_runtime.h>

// ============================================================================
// 2-layer tanh RNN, B=32, S=2048, D=H=O=512.
//  r5 = r3 skeleton (16 WGs, fused layers, K-eighth waves, LDS partials,
//       4 finisher waves) with two targeted changes:
//   (1) coherence scope sc0 sc1 (system) -> sc1 (device): ring/flag stores
//       stop at MALL instead of write-through past it; loads read MALL.
//   (2) poll-pressure cut: ONE poller wave per WG reads the group's 32 flag
//       lines (256B apart); other waves spin on an LDS mailbox. dout stores
//       moved after the flag store (off the release-drain critical path).
// ============================================================================

typedef short v8s __attribute__((ext_vector_type(8)));
typedef int   v4i __attribute__((ext_vector_type(4)));
typedef float v4f __attribute__((ext_vector_type(4)));

#define B_  32
#define S_  2048
#define DH  512
#define RM  3                 // ring depth 4

// ws layout (bytes)
#define FLAGS_OFF 0                       // 64 flag lines x 256B = 16KB
#define BIAS_OFF  16384                   // [2][512] f32 (b_ih + b_hh)
#define H0_OFF    24576                   // 4 slots x 64KB (hi[32][512]+lo[32][512])
#define H1_OFF    (H0_OFF + 4 * 65536)
#define WOUT_OFF  (H1_OFF + 4 * 65536)    // w_out bf16 [512][512]
#define WIH0_OFF  (WOUT_OFF + 524288)     // w_ih[0] bf16 [512][512]
#define SLOT_U    32768                   // ushorts per ring slot (hi+lo)
#define LO_U      16384                   // lo-plane offset (ushorts)

#define PART_BYTES (8 * 3 * 4 * 64 * 16)  // 96KB partials

static __device__ __forceinline__ unsigned short f2bf(float f) {  // RNE
  unsigned int u = __builtin_bit_cast(unsigned int, f);
  u += 0x7fffu + ((u >> 16) & 1u);
  return (unsigned short)(u >> 16);
}
static __device__ __forceinline__ float bf2f(unsigned short h) {
  return __builtin_bit_cast(float, ((unsigned int)h) << 16);
}
static __device__ __forceinline__ v8s pack8(float4 f0, float4 f1) {
  v8s r;
  r[0] = (short)f2bf(f0.x); r[1] = (short)f2bf(f0.y);
  r[2] = (short)f2bf(f0.z); r[3] = (short)f2bf(f0.w);
  r[4] = (short)f2bf(f1.x); r[5] = (short)f2bf(f1.y);
  r[6] = (short)f2bf(f1.z); r[7] = (short)f2bf(f1.w);
  return r;
}
static __device__ __forceinline__ float fast_tanh(float v) {
  float c = fminf(15.f, fmaxf(-15.f, v));
  float e = __expf(2.f * c);
  return (e - 1.f) * __builtin_amdgcn_rcpf(e + 1.f);
}

// ---- device-scope (MALL-coherent, cache-bypassing) accessors ---------------
static __device__ __forceinline__ v8s ld16c(const void* p) {
  v4i r;
  asm volatile("global_load_dwordx4 %0, %1, off sc1"
               : "=v"(r) : "v"(p) : "memory");
  return __builtin_bit_cast(v8s, r);
}
static __device__ __forceinline__ float ld4(const void* p) {  // cached, counted
  float r;
  asm volatile("global_load_dword %0, %1, off"
               : "=v"(r) : "v"(p) : "memory");
  return r;
}
static __device__ __forceinline__ void st16u(void* p, unsigned short v) {
  unsigned int vv = v;
  asm volatile("global_store_short %0, %1, off sc1"
               :: "v"(p), "v"(vv) : "memory");
}
static __device__ __forceinline__ void st32u(void* p, int v) {
  asm volatile("global_store_dword %0, %1, off sc1"
               :: "v"(p), "v"(v) : "memory");
}
static __device__ __forceinline__ int ld_flag(const int* p) {
  int r;
  asm volatile("global_load_dword %0, %1, off sc1\n\ts_waitcnt vmcnt(0)"
               : "=v"(r) : "v"(p) : "memory");
  return r;
}
static __device__ __forceinline__ void wait_vm0() {
  asm volatile("s_waitcnt vmcnt(0)" ::: "memory");
}
#define WAITN(N) do { asm volatile("s_waitcnt vmcnt(" #N ")" ::: "memory"); \
    __builtin_amdgcn_sched_barrier(0); } while (0)

// ---------------------------------------------------------------------------
__global__ void rnn_init(const float* __restrict__ hidden,
                         const float* __restrict__ b_ih,
                         const float* __restrict__ b_hh,
                         const float* __restrict__ w_out,
                         const float* __restrict__ w_ih,
                         int* __restrict__ flags,
                         float* __restrict__ bias,
                         unsigned short* __restrict__ h0ring,
                         unsigned short* __restrict__ h1ring,
                         unsigned short* __restrict__ woutbf,
                         unsigned short* __restrict__ wih0bf) {
  int i = blockIdx.x * blockDim.x + threadIdx.x;
  int nth = gridDim.x * blockDim.x;
  for (int t = i; t < 4096; t += nth) flags[t] = 0;
  for (int t = i; t < 1024; t += nth) bias[t] = b_ih[t] + b_hh[t];
  for (int t = i; t < 2 * B_ * DH; t += nth) {     // hidden -> ring slot 3
    int l = t >> 14;
    int off = t & 16383;
    float v = hidden[t];
    unsigned short hv = f2bf(v);
    unsigned short lv = f2bf(v - bf2f(hv));
    unsigned short* ring = l ? h1ring : h0ring;
    ring[3 * SLOT_U + off] = hv;
    ring[3 * SLOT_U + LO_U + off] = lv;
  }
  for (int t = i; t < 512 * 512; t += nth) {
    woutbf[t] = f2bf(w_out[t]);
    wih0bf[t] = f2bf(w_ih[t]);
  }
}

// ---------------------------------------------------------------------------
// Bulk projection: dst[r][:] = src[r][:] @ wb^T + bias (64 rows/WG, in-place ok)
__global__ __launch_bounds__(512) void proj64(
    const float* __restrict__ src,
    float* __restrict__ dst,
    const unsigned short* __restrict__ wb,
    const float* __restrict__ bias) {
  __shared__ unsigned short lds[64 * 512];
  const int tid = threadIdx.x;
  const int wid = tid >> 6;
  const int lane = tid & 63;
  const size_t row0 = (size_t)blockIdx.x * 64;

  #pragma unroll
  for (int it = 0; it < 8; ++it) {
    int c = it * 512 + tid;
    int row = c >> 6;
    int col8 = c & 63;
    const float4* s4 = (const float4*)(src + (row0 + row) * DH + col8 * 8);
    float4 f0 = s4[0], f1 = s4[1];
    v8s t = pack8(f0, f1);
    int byteoff = row * 1024 + ((col8 * 16) ^ ((row & 7) << 4));
    *(v8s*)((char*)lds + byteoff) = t;
  }
  __syncthreads();

  const int l15 = lane & 15;
  const int kq = (lane >> 4) * 8;

  for (int nt = wid; nt < 32; nt += 8) {
    v4f acc[4];
    #pragma unroll
    for (int mt = 0; mt < 4; ++mt) acc[mt] = (v4f){0.f, 0.f, 0.f, 0.f};
    const unsigned short* wr = wb + (size_t)(nt * 16 + l15) * 512;
    #pragma unroll
    for (int ks = 0; ks < 16; ++ks) {
      int kk = ks * 32 + kq;
      v8s bfrag = *(const v8s*)(wr + kk);
      #pragma unroll
      for (int mt = 0; mt < 4; ++mt) {
        int row = mt * 16 + l15;
        int byteoff = row * 1024 + ((kk * 2) ^ ((row & 7) << 4));
        v8s afrag = *(const v8s*)((char*)lds + byteoff);
        acc[mt] = __builtin_amdgcn_mfma_f32_16x16x32_bf16(afrag, bfrag, acc[mt], 0, 0, 0);
      }
    }
    float bo = bias[nt * 16 + l15];
    #pragma unroll
    for (int mt = 0; mt < 4; ++mt)
      #pragma unroll
      for (int r = 0; r < 4; ++r) {
        int row = mt * 16 + (lane >> 4) * 4 + r;
        int col = nt * 16 + l15;
        dst[(row0 + row) * DH + col] = acc[mt][r] + bo;
      }
  }
}

// ---------------------------------------------------------------------------
// Fused persistent kernel. wg = mh*8 + fs. mh: batch half (16 batches),
// fs: feature slice (64 feats, both layers). 8 waves = 8 K-eighths.
// Phase p: L0 computes h0(p) (p<2048), L1 computes h1(p-1) (p>=1).
// Wave 4 polls the group's 32 flag lines; others spin an LDS mailbox.
__global__ __launch_bounds__(512) void rnn_fused(
    const float* __restrict__ z0,     // d_out: Z0 (overwritten by h1/dout)
    const float* __restrict__ w_ih,
    const float* __restrict__ w_hh,
    const float* __restrict__ bias,
    unsigned short* __restrict__ h0ring,
    unsigned short* __restrict__ h1ring,
    int* __restrict__ flags,
    float* __restrict__ dout) {
  extern __shared__ char smem[];
  v4f* part = (v4f*)smem;                            // [8][3][4][64]
  int* gmb  = (int*)(smem + PART_BYTES);             // mailbox

  const int wg = blockIdx.x;
  const int mh = wg >> 3;               // batch half
  const int fs = wg & 7;                // feature slice (64 feats)

  const int tid = threadIdx.x;
  const int wid = tid >> 6;             // K-eighth
  const int lane = tid & 63;
  const int l15 = lane & 15;
  const int kq = (lane >> 4) * 8;
  const int q4 = (lane >> 4) * 4;

  // ---- resident weights: wfrag[g][n][ks], g: {w_hh0, w_ih1, w_hh1} --------
  v8s wfrag[3][4][2];
  {
    const float* wsrcs[3] = { w_hh, w_ih + 512 * 512, w_hh + 512 * 512 };
    #pragma unroll
    for (int g = 0; g < 3; ++g)
      #pragma unroll
      for (int n = 0; n < 4; ++n)
        #pragma unroll
        for (int ks = 0; ks < 2; ++ks) {
          const float* srow = wsrcs[g] +
              (size_t)(fs * 64 + n * 16 + l15) * 512 + wid * 64 + ks * 32 + kq;
          wfrag[g][n][ks] = pack8(*(const float4*)srow, *(const float4*)(srow + 4));
        }
  }
  const int nf = wid;                   // finisher n-tile (wid<4)
  const float bias1v = bias[512 + fs * 64 + (nf & 3) * 16 + l15];

  // per-lane A-frag base offset (batch row x 512 + wave K base)
  const size_t abase = (size_t)(mh * 16 + l15) * 512 + wid * 64 + kq;
  // finisher store offsets: batch = mh*16+q4+r, feat = fs*64+nf*16+l15
  const int featf = fs * 64 + (nf & 3) * 16 + l15;

  // flag lines: index (wg*4 + nf), 256B apart. Poller reads own group's 32.
  const int* fb = flags + (mh * 32 + (lane & 31)) * 64;
  int* const myflag = flags + (wg * 4 + (nf & 3)) * 64;

  if (tid == 0) *gmb = 0;
  __syncthreads();

  for (int p = 0; p <= S_; ++p) {
    // ---- gate: all own-group WGs finished phase p-1 ----------------------
    if (p >= 1) {
      if (wid == 4) {
        int v;
        do { v = ld_flag(fb); } while (!__all(v >= p));
        __hip_atomic_store(gmb, p, __ATOMIC_RELEASE, __HIP_MEMORY_SCOPE_WORKGROUP);
      } else {
        while (__hip_atomic_load(gmb, __ATOMIC_ACQUIRE,
                                 __HIP_MEMORY_SCOPE_WORKGROUP) < p) {}
      }
    }

    // ---- A-frag loads (device-scope) + z0 (cached, finishers) ------------
    const unsigned short* h0b = h0ring + (size_t)((p - 1) & RM) * SLOT_U + abase;
    const unsigned short* h1b = h1ring + (size_t)((p - 2) & RM) * SLOT_U + abase;
    v8s a0h[2], a0l[2], a1h[2], a1l[2];
    a0h[0] = ld16c(h0b);           a0l[0] = ld16c(h0b + LO_U);
    a0h[1] = ld16c(h0b + 32);      a0l[1] = ld16c(h0b + 32 + LO_U);
    a1h[0] = ld16c(h1b);           a1l[0] = ld16c(h1b + LO_U);
    a1h[1] = ld16c(h1b + 32);      a1l[1] = ld16c(h1b + 32 + LO_U);

    float zp[4];
    if (wid < 4) {
      const int pz = (p < S_) ? p : (S_ - 1);
      #pragma unroll
      for (int r = 0; r < 4; ++r)
        zp[r] = ld4(z0 + ((size_t)(mh * 16 + q4 + r) * S_ + pz) * DH + featf);
    }

    v4f acc[3][4];
    #pragma unroll
    for (int g = 0; g < 3; ++g)
      #pragma unroll
      for (int n = 0; n < 4; ++n) acc[g][n] = (v4f){0.f, 0.f, 0.f, 0.f};

    if (wid < 4) { WAITN(8); } else { WAITN(4); }     // h0 frags ready
    #pragma unroll
    for (int ks = 0; ks < 2; ++ks)
      #pragma unroll
      for (int n = 0; n < 4; ++n) {
        acc[0][n] = __builtin_amdgcn_mfma_f32_16x16x32_bf16(a0h[ks], wfrag[0][n][ks], acc[0][n], 0, 0, 0);
        acc[1][n] = __builtin_amdgcn_mfma_f32_16x16x32_bf16(a0h[ks], wfrag[1][n][ks], acc[1][n], 0, 0, 0);
      }
    #pragma unroll
    for (int ks = 0; ks < 2; ++ks)
      #pragma unroll
      for (int n = 0; n < 4; ++n) {
        acc[0][n] = __builtin_amdgcn_mfma_f32_16x16x32_bf16(a0l[ks], wfrag[0][n][ks], acc[0][n], 0, 0, 0);
        acc[1][n] = __builtin_amdgcn_mfma_f32_16x16x32_bf16(a0l[ks], wfrag[1][n][ks], acc[1][n], 0, 0, 0);
      }
    if (wid < 4) { WAITN(4); } else { WAITN(0); }     // h1 frags ready
    #pragma unroll
    for (int ks = 0; ks < 2; ++ks)
      #pragma unroll
      for (int n = 0; n < 4; ++n) {
        acc[2][n] = __builtin_amdgcn_mfma_f32_16x16x32_bf16(a1h[ks], wfrag[2][n][ks], acc[2][n], 0, 0, 0);
        acc[2][n] = __builtin_amdgcn_mfma_f32_16x16x32_bf16(a1l[ks], wfrag[2][n][ks], acc[2][n], 0, 0, 0);
      }

    // ---- K-reduction partials -------------------------------------------
    #pragma unroll
    for (int g = 0; g < 3; ++g)
      #pragma unroll
      for (int n = 0; n < 4; ++n)
        part[((wid * 3 + g) * 4 + n) * 64 + lane] = acc[g][n];
    __syncthreads();

    // ---- finishers: reduce, tanh, store rings, flag, then dout -----------
    if (wid < 4) {
      v4f s0 = {0.f,0.f,0.f,0.f}, s1 = {0.f,0.f,0.f,0.f}, s2 = {0.f,0.f,0.f,0.f};
      #pragma unroll
      for (int w = 0; w < 8; ++w) {
        s0 += part[((w * 3 + 0) * 4 + nf) * 64 + lane];
        s1 += part[((w * 3 + 1) * 4 + nf) * 64 + lane];
        s2 += part[((w * 3 + 2) * 4 + nf) * 64 + lane];
      }
      WAITN(0);                                       // zp ready
      float h0v[4], h1v[4];
      #pragma unroll
      for (int r = 0; r < 4; ++r) {
        h0v[r] = fast_tanh(zp[r] + s0[r]);
        h1v[r] = fast_tanh(s1[r] + s2[r] + bias1v);
      }
      if (p < S_) {                                   // store h0(p)
        unsigned short* dst = h0ring + (size_t)(p & RM) * SLOT_U;
        #pragma unroll
        for (int r = 0; r < 4; ++r) {
          unsigned short hv = f2bf(h0v[r]);
          unsigned short lv = f2bf(h0v[r] - bf2f(hv));
          size_t off = (size_t)(mh * 16 + q4 + r) * 512 + featf;
          st16u(dst + off, hv);
          st16u(dst + off + LO_U, lv);
        }
      }
      if (p >= 1) {                                   // store h1(p-1)
        unsigned short* dst = h1ring + (size_t)((p - 1) & RM) * SLOT_U;
        #pragma unroll
        for (int r = 0; r < 4; ++r) {
          unsigned short hv = f2bf(h1v[r]);
          unsigned short lv = f2bf(h1v[r] - bf2f(hv));
          size_t off = (size_t)(mh * 16 + q4 + r) * 512 + featf;
          st16u(dst + off, hv);
          st16u(dst + off + LO_U, lv);
        }
      }
      wait_vm0();                                     // ring stores at MALL
      st32u(myflag, p + 1);                           // release
      if (p >= 1) {                                   // dout off critical path
        #pragma unroll
        for (int r = 0; r < 4; ++r)
          dout[((size_t)(mh * 16 + q4 + r) * S_ + (p - 1)) * DH + featf] = h1v[r];
      }
    }
  }
}

// ---------------------------------------------------------------------------
extern "C" void kernel_launch(void* const* d_in, const int* in_sizes, int n_in,
                              void* d_out, int out_size, void* d_ws, size_t ws_size,
                              hipStream_t stream) {
  const float* x      = (const float*)d_in[0];
  const float* hidden = (const float*)d_in[1];
  const float* w_ih   = (const float*)d_in[2];
  const float* w_hh   = (const float*)d_in[3];
  const float* b_ih   = (const float*)d_in[4];
  const float* b_hh   = (const float*)d_in[5];
  const float* w_out  = (const float*)d_in[6];
  const float* b_out  = (const float*)d_in[7];
  float* out = (float*)d_out;

  char* wsb = (char*)d_ws;
  int* flags             = (int*)(wsb + FLAGS_OFF);
  float* bias            = (float*)(wsb + BIAS_OFF);
  unsigned short* h0ring = (unsigned short*)(wsb + H0_OFF);
  unsigned short* h1ring = (unsigned short*)(wsb + H1_OFF);
  unsigned short* woutbf = (unsigned short*)(wsb + WOUT_OFF);
  unsigned short* wih0bf = (unsigned short*)(wsb + WIH0_OFF);

  rnn_init<<<256, 256, 0, stream>>>(hidden, b_ih, b_hh, w_out, w_ih,
                                    flags, bias, h0ring, h1ring, woutbf, wih0bf);
  // Z0 = x @ w_ih0^T + (b_ih0 + b_hh0) -> d_out
  proj64<<<(B_ * S_) / 64, 512, 0, stream>>>(x, out, wih0bf, bias);
  rnn_fused<<<16, 512, PART_BYTES + 16, stream>>>(out, w_ih, w_hh, bias,
                                                  h0ring, h1ring, flags, out);
  // out = h1 @ w_out^T + b_out (in place)
  proj64<<<(B_ * S_) / 64, 512, 0, stream>>>(out, out, woutbf, b_out);
}

// Round 7
// 7184.886 us; speedup vs baseline: 1.3691x; 1.3691x over previous
//
#include <hip/hip_runtime.h>

// ============================================================================
// 2-layer tanh RNN, B=32, S=2048, D=H=O=512.
//  r6: self-synchronizing data. h exchanged as u32 = (hi_bf16<<16)|(lo_bf16&~7)
//      |epoch3 — every dword carries a 3-bit epoch tag, so consumers poll-load
//      the exact MFMA fragments they need and validate tags in the same load.
//      No producer drain, no flags, no mailbox, no barrier: stores are fire-
//      and-forget; data dependency itself bounds WG skew to 1 phase (each GEMM
//      needs ALL feature slices), so ring depth 4 + epoch mod 8 is unambiguous
//      (incl. across graph replays; init slot 3 tag 7 rewritten each launch).
//      Poll loops have a 2^15-retry cap -> 'bad' latch (no hangs, syncthreads
//      stay matched). Skeleton otherwise = r3/r5 (16 WGs fused layers,
//      8 K-eighth waves, LDS partials, 4 finisher waves).
// ============================================================================

typedef short v8s __attribute__((ext_vector_type(8)));
typedef int   v4i __attribute__((ext_vector_type(4)));
typedef float v4f __attribute__((ext_vector_type(4)));

#define B_  32
#define S_  2048
#define DH  512
#define SLOT32 16384                      // u32 per ring slot (32 x 512)

// ws layout (bytes)
#define BIAS_OFF  0                       // [2][512] f32 (b_ih + b_hh)
#define H0_OFF    8192                    // 4 slots x 64KB packed u32
#define H1_OFF    (H0_OFF + 4 * 65536)
#define WOUT_OFF  (H1_OFF + 4 * 65536)    // w_out bf16 [512][512]
#define WIH0_OFF  (WOUT_OFF + 524288)     // w_ih[0] bf16 [512][512]

#define PART_BYTES (8 * 3 * 4 * 64 * 16)  // 96KB LDS partials

static __device__ __forceinline__ unsigned short f2bf(float f) {  // RNE
  unsigned int u = __builtin_bit_cast(unsigned int, f);
  u += 0x7fffu + ((u >> 16) & 1u);
  return (unsigned short)(u >> 16);
}
static __device__ __forceinline__ float bf2f(unsigned short h) {
  return __builtin_bit_cast(float, ((unsigned int)h) << 16);
}
static __device__ __forceinline__ unsigned packh(float f, unsigned ep) {
  unsigned short hv = f2bf(f);
  unsigned short lv = f2bf(f - bf2f(hv));
  return ((unsigned)hv << 16) | ((unsigned)lv & 0xFFF8u) | ep;
}
static __device__ __forceinline__ v8s pack8(float4 f0, float4 f1) {
  v8s r;
  r[0] = (short)f2bf(f0.x); r[1] = (short)f2bf(f0.y);
  r[2] = (short)f2bf(f0.z); r[3] = (short)f2bf(f0.w);
  r[4] = (short)f2bf(f1.x); r[5] = (short)f2bf(f1.y);
  r[6] = (short)f2bf(f1.z); r[7] = (short)f2bf(f1.w);
  return r;
}
static __device__ __forceinline__ float fast_tanh(float v) {
  float c = fminf(15.f, fmaxf(-15.f, v));
  float e = __expf(2.f * c);
  return (e - 1.f) * __builtin_amdgcn_rcpf(e + 1.f);
}

// ---- device-scope (MALL) accessors ----------------------------------------
static __device__ __forceinline__ v4i ld16v(const unsigned* p) {
  v4i r;
  asm volatile("global_load_dwordx4 %0, %1, off sc1"
               : "=v"(r) : "v"(p) : "memory");
  return r;
}
static __device__ __forceinline__ float ld4(const void* p) {  // cached, counted
  float r;
  asm volatile("global_load_dword %0, %1, off"
               : "=v"(r) : "v"(p) : "memory");
  return r;
}
static __device__ __forceinline__ void st32u(void* p, unsigned v) {
  asm volatile("global_store_dword %0, %1, off sc1"
               :: "v"(p), "v"(v) : "memory");
}
#define WAITN0() do { asm volatile("s_waitcnt vmcnt(0)" ::: "memory"); \
    __builtin_amdgcn_sched_barrier(0); } while (0)

// Poll one matrix fragment set (16 u32/lane: ks0 kq..kq+7, ks1 kq..kq+7).
static __device__ __forceinline__ void poll_frag(const unsigned* b, unsigned ep,
                                                 bool* bad, v4i* o0, v4i* o1,
                                                 v4i* o2, v4i* o3) {
  v4i a0, a1, a2, a3;
  int t = 0;
  for (;;) {
    a0 = ld16v(b); a1 = ld16v(b + 4); a2 = ld16v(b + 32); a3 = ld16v(b + 36);
    WAITN0();
    if (*bad) break;
    unsigned d = 0;
    #pragma unroll
    for (int j = 0; j < 4; ++j)
      d |= ((unsigned)a0[j] ^ ep) | ((unsigned)a1[j] ^ ep)
         | ((unsigned)a2[j] ^ ep) | ((unsigned)a3[j] ^ ep);
    if (__all((d & 7u) == 0u)) break;
    if (++t > (1 << 15)) { *bad = true; break; }
  }
  *o0 = a0; *o1 = a1; *o2 = a2; *o3 = a3;
}
static __device__ __forceinline__ void unp(v4i a, v4i b, v8s* hi, v8s* lo) {
  v8s h, l;
  #pragma unroll
  for (int j = 0; j < 4; ++j) {
    unsigned ua = (unsigned)a[j], ub = (unsigned)b[j];
    h[j]     = (short)(ua >> 16);   l[j]     = (short)(ua & 0xFFF8u);
    h[4 + j] = (short)(ub >> 16);   l[4 + j] = (short)(ub & 0xFFF8u);
  }
  *hi = h; *lo = l;
}

// ---------------------------------------------------------------------------
__global__ void rnn_init(const float* __restrict__ hidden,
                         const float* __restrict__ b_ih,
                         const float* __restrict__ b_hh,
                         const float* __restrict__ w_out,
                         const float* __restrict__ w_ih,
                         float* __restrict__ bias,
                         unsigned* __restrict__ h0ring,
                         unsigned* __restrict__ h1ring,
                         unsigned short* __restrict__ woutbf,
                         unsigned short* __restrict__ wih0bf) {
  int i = blockIdx.x * blockDim.x + threadIdx.x;
  int nth = gridDim.x * blockDim.x;
  for (int t = i; t < 1024; t += nth) bias[t] = b_ih[t] + b_hh[t];
  for (int t = i; t < 2 * B_ * DH; t += nth) {     // initial h -> slot 3, tag 7
    int l = t >> 14;
    int off = t & 16383;
    unsigned* ring = l ? h1ring : h0ring;
    ring[3 * SLOT32 + off] = packh(hidden[t], 7u);
  }
  for (int t = i; t < 512 * 512; t += nth) {
    woutbf[t] = f2bf(w_out[t]);
    wih0bf[t] = f2bf(w_ih[t]);
  }
}

// ---------------------------------------------------------------------------
// Bulk projection: dst[r][:] = src[r][:] @ wb^T + bias (64 rows/WG, in-place ok)
__global__ __launch_bounds__(512) void proj64(
    const float* __restrict__ src,
    float* __restrict__ dst,
    const unsigned short* __restrict__ wb,
    const float* __restrict__ bias) {
  __shared__ unsigned short lds[64 * 512];
  const int tid = threadIdx.x;
  const int wid = tid >> 6;
  const int lane = tid & 63;
  const size_t row0 = (size_t)blockIdx.x * 64;

  #pragma unroll
  for (int it = 0; it < 8; ++it) {
    int c = it * 512 + tid;
    int row = c >> 6;
    int col8 = c & 63;
    const float4* s4 = (const float4*)(src + (row0 + row) * DH + col8 * 8);
    float4 f0 = s4[0], f1 = s4[1];
    v8s t = pack8(f0, f1);
    int byteoff = row * 1024 + ((col8 * 16) ^ ((row & 7) << 4));
    *(v8s*)((char*)lds + byteoff) = t;
  }
  __syncthreads();

  const int l15 = lane & 15;
  const int kq = (lane >> 4) * 8;

  for (int nt = wid; nt < 32; nt += 8) {
    v4f acc[4];
    #pragma unroll
    for (int mt = 0; mt < 4; ++mt) acc[mt] = (v4f){0.f, 0.f, 0.f, 0.f};
    const unsigned short* wr = wb + (size_t)(nt * 16 + l15) * 512;
    #pragma unroll
    for (int ks = 0; ks < 16; ++ks) {
      int kk = ks * 32 + kq;
      v8s bfrag = *(const v8s*)(wr + kk);
      #pragma unroll
      for (int mt = 0; mt < 4; ++mt) {
        int row = mt * 16 + l15;
        int byteoff = row * 1024 + ((kk * 2) ^ ((row & 7) << 4));
        v8s afrag = *(const v8s*)((char*)lds + byteoff);
        acc[mt] = __builtin_amdgcn_mfma_f32_16x16x32_bf16(afrag, bfrag, acc[mt], 0, 0, 0);
      }
    }
    float bo = bias[nt * 16 + l15];
    #pragma unroll
    for (int mt = 0; mt < 4; ++mt)
      #pragma unroll
      for (int r = 0; r < 4; ++r) {
        int row = mt * 16 + (lane >> 4) * 4 + r;
        int col = nt * 16 + l15;
        dst[(row0 + row) * DH + col] = acc[mt][r] + bo;
      }
  }
}

// ---------------------------------------------------------------------------
// Fused persistent kernel. wg = mh*8 + fs. 8 waves = 8 K-eighths.
// Phase p: GEMM0 Whh0*h0(p-1) -> h0(p); GEMM1 Wih1*h0(p-1) and
// GEMM2 Whh1*h1(p-2) -> h1(p-1). Waves 0-3 finish (reduce+tanh+store).
__global__ __launch_bounds__(512) void rnn_fused(
    const float* __restrict__ z0,     // d_out: Z0 (overwritten by dout)
    const float* __restrict__ w_ih,
    const float* __restrict__ w_hh,
    const float* __restrict__ bias,
    unsigned* __restrict__ h0ring,
    unsigned* __restrict__ h1ring,
    float* __restrict__ dout) {
  extern __shared__ char smem[];
  v4f* part = (v4f*)smem;               // [8][3][4][64]

  const int wg = blockIdx.x;
  const int mh = wg >> 3;               // batch half
  const int fs = wg & 7;                // feature slice (64 feats)

  const int tid = threadIdx.x;
  const int wid = tid >> 6;             // K-eighth
  const int lane = tid & 63;
  const int l15 = lane & 15;
  const int kq = (lane >> 4) * 8;
  const int q4 = (lane >> 4) * 4;

  // resident weights: wfrag[g][n][ks], g: {w_hh0, w_ih1, w_hh1}
  v8s wfrag[3][4][2];
  {
    const float* wsrcs[3] = { w_hh, w_ih + 512 * 512, w_hh + 512 * 512 };
    #pragma unroll
    for (int g = 0; g < 3; ++g)
      #pragma unroll
      for (int n = 0; n < 4; ++n)
        #pragma unroll
        for (int ks = 0; ks < 2; ++ks) {
          const float* srow = wsrcs[g] +
              (size_t)(fs * 64 + n * 16 + l15) * 512 + wid * 64 + ks * 32 + kq;
          wfrag[g][n][ks] = pack8(*(const float4*)srow, *(const float4*)(srow + 4));
        }
  }
  const int nf = wid & 3;               // finisher n-tile (wid<4)
  const float bias1v = bias[512 + fs * 64 + nf * 16 + l15];
  const size_t abase = (size_t)(mh * 16 + l15) * 512 + wid * 64 + kq;
  const int featf = fs * 64 + nf * 16 + l15;

  bool bad = false;

  for (int p = 0; p <= S_; ++p) {
    // ---- z0 issue (finishers; drains inside first poll wait) --------------
    float zp[4];
    if (wid < 4) {
      const int pz = (p < S_) ? p : (S_ - 1);
      #pragma unroll
      for (int r = 0; r < 4; ++r)
        zp[r] = ld4(z0 + ((size_t)(mh * 16 + q4 + r) * S_ + pz) * DH + featf);
    }

    // ---- poll h0(p-1), GEMM0/1 --------------------------------------------
    const unsigned ep0 = (p == 0) ? 7u : (unsigned)(((p - 1) >> 2) & 7);
    const unsigned* h0b = h0ring + (size_t)((p + 3) & 3) * SLOT32 + abase;
    v4i A0, A1, A2, A3;
    poll_frag(h0b, ep0, &bad, &A0, &A1, &A2, &A3);
    v8s h0h0, h0l0, h0h1, h0l1;
    unp(A0, A1, &h0h0, &h0l0);
    unp(A2, A3, &h0h1, &h0l1);

    v4f acc0[4], acc1[4], acc2[4];
    #pragma unroll
    for (int n = 0; n < 4; ++n) {
      acc0[n] = (v4f){0.f, 0.f, 0.f, 0.f};
      acc1[n] = (v4f){0.f, 0.f, 0.f, 0.f};
      acc2[n] = (v4f){0.f, 0.f, 0.f, 0.f};
    }
    #pragma unroll
    for (int n = 0; n < 4; ++n) {
      acc0[n] = __builtin_amdgcn_mfma_f32_16x16x32_bf16(h0h0, wfrag[0][n][0], acc0[n], 0, 0, 0);
      acc0[n] = __builtin_amdgcn_mfma_f32_16x16x32_bf16(h0l0, wfrag[0][n][0], acc0[n], 0, 0, 0);
      acc0[n] = __builtin_amdgcn_mfma_f32_16x16x32_bf16(h0h1, wfrag[0][n][1], acc0[n], 0, 0, 0);
      acc0[n] = __builtin_amdgcn_mfma_f32_16x16x32_bf16(h0l1, wfrag[0][n][1], acc0[n], 0, 0, 0);
      acc1[n] = __builtin_amdgcn_mfma_f32_16x16x32_bf16(h0h0, wfrag[1][n][0], acc1[n], 0, 0, 0);
      acc1[n] = __builtin_amdgcn_mfma_f32_16x16x32_bf16(h0l0, wfrag[1][n][0], acc1[n], 0, 0, 0);
      acc1[n] = __builtin_amdgcn_mfma_f32_16x16x32_bf16(h0h1, wfrag[1][n][1], acc1[n], 0, 0, 0);
      acc1[n] = __builtin_amdgcn_mfma_f32_16x16x32_bf16(h0l1, wfrag[1][n][1], acc1[n], 0, 0, 0);
    }

    // ---- poll h1(p-2), GEMM2 (skip at p==0: result discarded) -------------
    if (p >= 1) {
      const unsigned ep1 = (p == 1) ? 7u : (unsigned)(((p - 2) >> 2) & 7);
      const unsigned* h1b = h1ring + (size_t)((p + 2) & 3) * SLOT32 + abase;
      v4i B0, B1, B2, B3;
      poll_frag(h1b, ep1, &bad, &B0, &B1, &B2, &B3);
      v8s h1h0, h1l0, h1h1, h1l1;
      unp(B0, B1, &h1h0, &h1l0);
      unp(B2, B3, &h1h1, &h1l1);
      #pragma unroll
      for (int n = 0; n < 4; ++n) {
        acc2[n] = __builtin_amdgcn_mfma_f32_16x16x32_bf16(h1h0, wfrag[2][n][0], acc2[n], 0, 0, 0);
        acc2[n] = __builtin_amdgcn_mfma_f32_16x16x32_bf16(h1l0, wfrag[2][n][0], acc2[n], 0, 0, 0);
        acc2[n] = __builtin_amdgcn_mfma_f32_16x16x32_bf16(h1h1, wfrag[2][n][1], acc2[n], 0, 0, 0);
        acc2[n] = __builtin_amdgcn_mfma_f32_16x16x32_bf16(h1l1, wfrag[2][n][1], acc2[n], 0, 0, 0);
      }
    }

    // ---- K-reduction partials ---------------------------------------------
    #pragma unroll
    for (int n = 0; n < 4; ++n) {
      part[((wid * 3 + 0) * 4 + n) * 64 + lane] = acc0[n];
      part[((wid * 3 + 1) * 4 + n) * 64 + lane] = acc1[n];
      part[((wid * 3 + 2) * 4 + n) * 64 + lane] = acc2[n];
    }
    __syncthreads();

    // ---- finishers: reduce, tanh, pack+tag, fire-and-forget stores --------
    if (wid < 4) {
      v4f s0 = {0.f,0.f,0.f,0.f}, s1 = {0.f,0.f,0.f,0.f}, s2 = {0.f,0.f,0.f,0.f};
      #pragma unroll
      for (int w = 0; w < 8; ++w) {
        s0 += part[((w * 3 + 0) * 4 + nf) * 64 + lane];
        s1 += part[((w * 3 + 1) * 4 + nf) * 64 + lane];
        s2 += part[((w * 3 + 2) * 4 + nf) * 64 + lane];
      }
      float h0v[4], h1v[4];
      #pragma unroll
      for (int r = 0; r < 4; ++r) {
        h0v[r] = fast_tanh(zp[r] + s0[r]);
        h1v[r] = fast_tanh(s1[r] + s2[r] + bias1v);
      }
      if (p < S_) {                                   // h0(p), tag (p>>2)&7
        const unsigned ep = (unsigned)((p >> 2) & 7);
        unsigned* dst = h0ring + (size_t)(p & 3) * SLOT32;
        #pragma unroll
        for (int r = 0; r < 4; ++r)
          st32u(dst + (size_t)(mh * 16 + q4 + r) * 512 + featf, packh(h0v[r], ep));
      }
      if (p >= 1) {                                   // h1(p-1), tag ((p-1)>>2)&7
        const unsigned ep = (unsigned)(((p - 1) >> 2) & 7);
        unsigned* dst = h1ring + (size_t)((p - 1) & 3) * SLOT32;
        #pragma unroll
        for (int r = 0; r < 4; ++r) {
          st32u(dst + (size_t)(mh * 16 + q4 + r) * 512 + featf, packh(h1v[r], ep));
          dout[((size_t)(mh * 16 + q4 + r) * S_ + (p - 1)) * DH + featf] = h1v[r];
        }
      }
    }
    __syncthreads();   // keep LDS partials stable until finishers consumed them
  }
}

// ---------------------------------------------------------------------------
extern "C" void kernel_launch(void* const* d_in, const int* in_sizes, int n_in,
                              void* d_out, int out_size, void* d_ws, size_t ws_size,
                              hipStream_t stream) {
  const float* x      = (const float*)d_in[0];
  const float* hidden = (const float*)d_in[1];
  const float* w_ih   = (const float*)d_in[2];
  const float* w_hh   = (const float*)d_in[3];
  const float* b_ih   = (const float*)d_in[4];
  const float* b_hh   = (const float*)d_in[5];
  const float* w_out  = (const float*)d_in[6];
  const float* b_out  = (const float*)d_in[7];
  float* out = (float*)d_out;

  char* wsb = (char*)d_ws;
  float* bias            = (float*)(wsb + BIAS_OFF);
  unsigned* h0ring       = (unsigned*)(wsb + H0_OFF);
  unsigned* h1ring       = (unsigned*)(wsb + H1_OFF);
  unsigned short* woutbf = (unsigned short*)(wsb + WOUT_OFF);
  unsigned short* wih0bf = (unsigned short*)(wsb + WIH0_OFF);

  rnn_init<<<256, 256, 0, stream>>>(hidden, b_ih, b_hh, w_out, w_ih,
                                    bias, h0ring, h1ring, woutbf, wih0bf);
  // Z0 = x @ w_ih0^T + (b_ih0 + b_hh0) -> d_out
  proj64<<<(B_ * S_) / 64, 512, 0, stream>>>(x, out, wih0bf, bias);
  rnn_fused<<<16, 512, PART_BYTES, stream>>>(out, w_ih, w_hh, bias,
                                             h0ring, h1ring, out);
  // out = h1 @ w_out^T + b_out (in place)
  proj64<<<(B_ * S_) / 64, 512, 0, stream>>>(out, out, woutbf, b_out);
}